// Round 4
// baseline (575.836 us; speedup 1.0000x reference)
//
#include <hip/hip_runtime.h>
#include <hip/hip_bf16.h>

#define DD 128
#define KK 256
#define TS 256        // samples per stage-3 tile
#define ROWB 136      // padded LDS row stride (bf16 elems)
#define SPB1 1024     // samples per stage-1 block

typedef __attribute__((ext_vector_type(8))) short short8;
typedef __attribute__((ext_vector_type(4))) float f32x4;

static __device__ __forceinline__ unsigned short f2bf(float f) {
    unsigned int u = __float_as_uint(f);
    return (unsigned short)((u + 0x7fffu + ((u >> 16) & 1u)) >> 16);   // RNE
}
static __device__ __forceinline__ float bf2f(unsigned short h) {
    return __uint_as_float(((unsigned int)h) << 16);
}

// ---------------- stage 1 (R8): streaming + LDS-atomic accumulate ----------------
// R3 lesson: the counting-sort gather was ~170us (vs ~35us roofline) — latency-bound
// permuted row walk + sort preamble. The per-block accumulator (256x128 f32 = 128KB)
// fits in LDS, so: stream rows SEQUENTIALLY (coalesced, BW-optimal), ds_add_f32 into
// Csh[label*128 + 2*lane]. Banks = 2*lane -> conflict-free; cross-wave collisions on
// the same cluster are rare (random labels) and handled by the atomic.
// Summation order is nondeterministic — but so was the old cursor-atomicAdd order,
// and absmax has been 0.0 throughout; harness tolerance absorbs last-bit noise.
// MODE 0: per-block partial slot.  MODE 2: global-atomic merge (tiny-ws fallback).
template<int MODE>
__global__ __launch_bounds__(1024) void k_stage1_accum(
    const float* __restrict__ X, const int* __restrict__ labels,
    float* __restrict__ partial)
{
    __shared__ float Csh[KK * DD];          // 128 KB accumulator
    __shared__ int   labs_s[SPB1];          // 4 KB

    const int tid  = threadIdx.x;
    const int lane = tid & 63;
    const int wave = tid >> 6;              // 0..15
    const int base = blockIdx.x * SPB1;

#pragma unroll
    for (int i = 0; i < KK * DD / 1024; ++i)     // zero 32K floats, 32/thread
        Csh[tid + (i << 10)] = 0.f;
    labs_s[tid] = labels[base + tid];
    __syncthreads();

    // wave w owns rows w, w+16, ... : adjacent waves read adjacent rows (L2-friendly)
    const float2* X2 = (const float2*)(X + (size_t)base * DD);
#pragma unroll 4
    for (int r = wave; r < SPB1; r += 16) {
        const float2 v = X2[(size_t)r * 64 + lane];   // coalesced 512B per wave
        const int l = labs_s[r];                      // LDS broadcast
        atomicAdd(&Csh[l * DD + 2 * lane],     v.x);  // ds_add_f32, no return
        atomicAdd(&Csh[l * DD + 2 * lane + 1], v.y);
    }
    __syncthreads();

    if (MODE == 2) {
        for (int i = tid; i < KK * DD; i += 1024)
            atomicAdd(&partial[i], Csh[i]);
    } else {
        float4* dst = (float4*)(partial + (size_t)blockIdx.x * KK * DD);
        const float4* src = (const float4*)Csh;
#pragma unroll
        for (int i = 0; i < KK * DD / 4 / 1024; ++i)  // 8 x float4 per thread, coalesced
            dst[tid + (i << 10)] = src[tid + (i << 10)];
    }
}

// ---------------- stage 2: reduce partials, normalize (counts cancel), emit bf16 ----------------
__global__ void k_stage2(const float* __restrict__ partial, int nparts,
                         unsigned short* __restrict__ centb)
{
    const int k = blockIdx.x;
    const int t = threadIdx.x;      // 512
    const int d = t & (DD - 1);
    const int slice = t >> 7;
    float s = 0.f;
    for (int b = slice; b < nparts; b += 4)
        s += partial[((size_t)b * KK + k) * DD + d];
    __shared__ float red[4][DD];
    red[slice][d] = s;
    __syncthreads();
    float v = 0.f;
    if (t < DD) v = red[0][d] + red[1][d] + red[2][d] + red[3][d];
    float sq = v * v;
#pragma unroll
    for (int m = 32; m > 0; m >>= 1) sq += __shfl_xor(sq, m);
    __shared__ float wsum[8];
    if ((t & 63) == 0) wsum[t >> 6] = sq;
    __syncthreads();
    if (t < DD) centb[k * DD + d] = f2bf(v * rsqrtf(wsum[0] + wsum[1]));
}

// ---------------- stage 3: R0-verbatim fused X@C^T MFMA + loss (known-good 76us) ----------------
// R2/R3 lesson: at 1024 thr/block (128-VGPR cap) there is NO register headroom for
// cross-phase prefetch (acc=64 + 32 staging regs spills). The simple staged loop with
// short live ranges is near-optimal for this shape — restored exactly.
__global__ __launch_bounds__(1024, 4) void k_stage3(
    const float* __restrict__ Xf, const int* __restrict__ labels,
    const unsigned short* __restrict__ centb,
    const float* __restrict__ hbias, float* __restrict__ loss, int spb)
{
    __shared__ unsigned short Cl[KK * ROWB];
    __shared__ unsigned short Xl[TS * ROWB];
    __shared__ int   labs[TS];
    __shared__ float lred[32];

    const int tid = threadIdx.x;
    const float hb = *hbias;
    const float bias = (hb > 20.f) ? hb : log1pf(__expf(hb));
    const float pos_bias = bias;
    const float neg_bias = 9.f * bias + 0.05f;

    const uint4* csrc = (const uint4*)centb;
    for (int c = tid; c < KK * DD / 8; c += 1024) {
        const int row = c >> 4;
        const int col = (c & 15) << 3;
        *(uint4*)(&Cl[row * ROWB + col]) = csrc[c];
    }

    const int lane = tid & 63;
    const int wave = tid >> 6;       // 0..15
    const int m15  = lane & 15;
    const int q    = lane >> 4;
    const int kq   = q << 3;
    const int base = blockIdx.x * spb;
    float pos_acc = 0.f, neg_acc = 0.f;

    for (int t0 = 0; t0 < spb; t0 += TS) {
        __syncthreads();
        const float4* xsrc = (const float4*)(Xf + (size_t)(base + t0) * DD);
        for (int c = tid; c < TS * DD / 4; c += 1024) {
            const int row = c >> 5;
            const int col = (c & 31) << 2;
            const float4 v = xsrc[c];
            ushort4 pk = make_ushort4(f2bf(v.x), f2bf(v.y), f2bf(v.z), f2bf(v.w));
            *(ushort4*)(&Xl[row * ROWB + col]) = pk;
        }
        if (tid < TS) labs[tid] = labels[base + t0 + tid];
        __syncthreads();

        short8 afrag[4];
        const int arow = (wave << 4) + m15;
#pragma unroll
        for (int s = 0; s < 4; ++s)
            afrag[s] = *(const short8*)(&Xl[arow * ROWB + (s << 5) + kq]);

        float x2p = 0.f;
#pragma unroll
        for (int s = 0; s < 4; ++s)
#pragma unroll
            for (int j = 0; j < 8; ++j) {
                const float e = bf2f((unsigned short)afrag[s][j]);
                x2p = fmaf(e, e, x2p);
            }
        x2p += __shfl_xor(x2p, 16);
        x2p += __shfl_xor(x2p, 32);

        f32x4 acc[16];
#pragma unroll
        for (int t = 0; t < 16; ++t) acc[t] = (f32x4){0.f, 0.f, 0.f, 0.f};
#pragma unroll
        for (int t = 0; t < 16; ++t) {
            const int brow = (t << 4) + m15;
#pragma unroll
            for (int s = 0; s < 4; ++s) {
                const short8 bfrag = *(const short8*)(&Cl[brow * ROWB + (s << 5) + kq]);
                acc[t] = __builtin_amdgcn_mfma_f32_16x16x32_bf16(afrag[s], bfrag, acc[t], 0, 0, 0);
            }
        }

#pragma unroll
        for (int r = 0; r < 4; ++r) {
            const int ml = (wave << 4) + (q << 2) + r;
            const int l  = labs[ml];
            const float x2 = __shfl(x2p, (q << 2) + r, 16);
            float posd = -1e30f, negd = -1e30f;
#pragma unroll
            for (int t = 0; t < 16; ++t) {
                const int cl = (t << 4) + m15;
                const float v = acc[t][r];
                const bool isp = (cl == l);
                posd = isp ? v : posd;
                negd = isp ? negd : fmaxf(negd, v);
            }
#pragma unroll
            for (int m = 1; m < 16; m <<= 1) {
                posd = fmaxf(posd, __shfl_xor(posd, m));
                negd = fmaxf(negd, __shfl_xor(negd, m));
            }
            if (m15 == 0) {
                const float pd = x2 + 1.0f - 2.f * posd;
                const float nd = x2 + 1.0f - 2.f * negd;
                pos_acc += fmaxf(pd - pos_bias, 0.f);
                neg_acc += fmaxf(neg_bias - nd, 0.f);
            }
        }
    }

#pragma unroll
    for (int m = 32; m > 0; m >>= 1) {
        pos_acc += __shfl_xor(pos_acc, m);
        neg_acc += __shfl_xor(neg_acc, m);
    }
    if (lane == 0) { lred[wave] = pos_acc; lred[16 + wave] = neg_acc; }
    __syncthreads();
    if (tid == 0) {
        float p = 0.f, n = 0.f;
#pragma unroll
        for (int w = 0; w < 16; ++w) { p += lred[w]; n += lred[16 + w]; }
        atomicAdd(&loss[0], p);
        atomicAdd(&loss[1], n);
    }
}

__global__ void k_final(const float* __restrict__ loss, float* __restrict__ out, float invN)
{
    if (threadIdx.x == 0) {
        out[0] = 4.0f * loss[0] * invN;
        out[1] = loss[1] * invN;
    }
}

extern "C" void kernel_launch(void* const* d_in, const int* in_sizes, int n_in,
                              void* d_out, int out_size, void* d_ws, size_t ws_size,
                              hipStream_t stream)
{
    const float* X      = (const float*)d_in[0];
    // d_in[1] (scores) is dead in the reference forward — never read.
    const int*   labels = (const int*)d_in[2];
    const float* hbias  = (const float*)d_in[3];
    float* out = (float*)d_out;
    const int N = in_sizes[0] / DD;
    const int G = N / SPB1;                   // 256 blocks

    char* ws = (char*)d_ws;
    const size_t offC    = 256;
    const size_t offPart = offC + (size_t)KK * DD * 2;
    const size_t szPart  = (size_t)G * KK * DD * 4;    // 32 MiB

    float*          loss    = (float*)ws;
    unsigned short* centb   = (unsigned short*)(ws + offC);
    float*          partial = (float*)(ws + offPart);

    const int mode   = (ws_size >= offPart + szPart) ? 0 : 2;
    const int nparts = (mode == 2) ? 1 : G;

    hipMemsetAsync(loss, 0, 2 * sizeof(float), stream);
    if (mode == 2) hipMemsetAsync(partial, 0, (size_t)KK * DD * 4, stream);

    if (mode == 0) k_stage1_accum<0><<<G, 1024, 0, stream>>>(X, labels, partial);
    else           k_stage1_accum<2><<<G, 1024, 0, stream>>>(X, labels, partial);

    k_stage2<<<KK, 512, 0, stream>>>(partial, nparts, centb);

    k_stage3<<<G, 1024, 0, stream>>>(X, labels, centb, hbias, loss, N / G);

    k_final<<<1, 64, 0, stream>>>(loss, out, 1.0f / (float)N);
}

// Round 5
// 451.142 us; speedup vs baseline: 1.2764x; 1.2764x over previous
//
#include <hip/hip_runtime.h>
#include <hip/hip_bf16.h>

#define DD 128
#define KK 256
#define TS 256        // samples per stage-3 tile
#define ROWB 136      // padded LDS row stride (bf16 elems)
#define SPB1 1024     // samples per stage-1 block

typedef __attribute__((ext_vector_type(8))) short short8;
typedef __attribute__((ext_vector_type(4))) float f32x4;

// Session time ledger (reconciled exactly across R0-R4):
//   fill 161 | stage1 sort-gather ~70 | stage3 R0-form ~76 | stage2+small-dispatches+gaps ~159
// R4 lesson: LDS-atomic scatter (179us) LOSES to counting-sort gather (70us) — latency
// serialization of load->ds_add chains. Reverted. This round attacks the 159us tail.

static __device__ __forceinline__ unsigned short f2bf(float f) {
    unsigned int u = __float_as_uint(f);
    return (unsigned short)((u + 0x7fffu + ((u >> 16) & 1u)) >> 16);   // RNE
}
static __device__ __forceinline__ float bf2f(unsigned short h) {
    return __uint_as_float(((unsigned int)h) << 16);
}

// ---------------- stage 1: counting-sort gather, 8-deep load pipeline (R3, known ~70us) ----------------
// MODE 0: per-block partial slot.  MODE 2: global-atomic merge (tiny-ws fallback).
template<int MODE>
__global__ __launch_bounds__(1024) void k_stage1_gather(
    const float* __restrict__ X, const int* __restrict__ labels,
    float* __restrict__ partial)
{
    __shared__ int lab[SPB1];
    __shared__ int idx[SPB1];
    __shared__ int hist[KK];
    __shared__ int start[KK + 1];
    __shared__ int cursor[KK];

    const int tid  = threadIdx.x;
    const int lane = tid & 63;
    const int wave = tid >> 6;
    const int base = blockIdx.x * SPB1;

    if (tid < KK) hist[tid] = 0;
    __syncthreads();
    {
        const int l = labels[base + tid];
        lab[tid] = l;
        atomicAdd(&hist[l], 1);
    }
    __syncthreads();
    if (wave == 0) {                        // exclusive scan of 256 bins in one wave
        const int h0 = hist[4*lane], h1 = hist[4*lane+1];
        const int h2 = hist[4*lane+2], h3 = hist[4*lane+3];
        const int s = h0 + h1 + h2 + h3;
        int t = s;
#pragma unroll
        for (int d = 1; d < 64; d <<= 1) { const int u = __shfl_up(t, d); if (lane >= d) t += u; }
        const int e = t - s;
        start[4*lane]   = e;
        start[4*lane+1] = e + h0;
        start[4*lane+2] = e + h0 + h1;
        start[4*lane+3] = e + h0 + h1 + h2;
        if (lane == 63) start[KK] = t;
    }
    __syncthreads();
    if (tid < KK) cursor[tid] = start[tid];
    __syncthreads();
    {
        const int pos = atomicAdd(&cursor[lab[tid]], 1);
        idx[pos] = tid;
    }
    __syncthreads();

    // wave w owns contiguous clusters [16w, 16w+16); flat member walk, 8 loads in flight
    const int c1 = (wave << 4) + 16;
    int c = wave << 4;
    const int s0 = start[c], s1 = start[c1];
    const int cnt = s1 - s0;
    int nx = start[c + 1];                  // register-cached cluster boundary

    float2 pf[8];
#pragma unroll
    for (int j = 0; j < 8; ++j)
        if (j < cnt)
            pf[j] = *(const float2*)(X + (size_t)(base + idx[s0 + j]) * DD + 2 * lane);

    float2 acc = make_float2(0.f, 0.f);
    int i = 0;
    for (; i + 8 <= cnt; i += 8) {
#pragma unroll
        for (int j = 0; j < 8; ++j) {
            const float2 v = pf[j];
            if (i + j + 8 < cnt)
                pf[j] = *(const float2*)(X + (size_t)(base + idx[s0 + i + j + 8]) * DD + 2 * lane);
            while (s0 + i + j >= nx) {       // wave-uniform boundary flush
                if (MODE == 2) {
                    atomicAdd(&partial[(size_t)c * DD + 2*lane],     acc.x);
                    atomicAdd(&partial[(size_t)c * DD + 2*lane + 1], acc.y);
                } else {
                    *(float2*)(partial + ((size_t)blockIdx.x * KK + c) * DD + 2*lane) = acc;
                }
                acc = make_float2(0.f, 0.f); ++c; nx = start[c + 1];
            }
            acc.x += v.x; acc.y += v.y;
        }
    }
#pragma unroll
    for (int j = 0; j < 8; ++j) {                       // tail (<8 rows), pf[j] = row i+j
        if (i + j < cnt) {
            const float2 v = pf[j];
            while (s0 + i + j >= nx) {
                if (MODE == 2) {
                    atomicAdd(&partial[(size_t)c * DD + 2*lane],     acc.x);
                    atomicAdd(&partial[(size_t)c * DD + 2*lane + 1], acc.y);
                } else {
                    *(float2*)(partial + ((size_t)blockIdx.x * KK + c) * DD + 2*lane) = acc;
                }
                acc = make_float2(0.f, 0.f); ++c; nx = start[c + 1];
            }
            acc.x += v.x; acc.y += v.y;
        }
    }
    while (c < c1) {                                    // flush trailing (incl. empty) clusters
        if (MODE == 2) {
            atomicAdd(&partial[(size_t)c * DD + 2*lane],     acc.x);
            atomicAdd(&partial[(size_t)c * DD + 2*lane + 1], acc.y);
        } else {
            *(float2*)(partial + ((size_t)blockIdx.x * KK + c) * DD + 2*lane) = acc;
        }
        acc = make_float2(0.f, 0.f); ++c;
    }
}

// ---------------- stage 2 (R9): reduce partials with 4-deep MLP, normalize, emit bf16 ----------------
// Old loop was one-load-in-flight (latency chain over 64 strided 512B reads).
// 4 independent accumulators -> 16 loads in flight -> BW-bound.
__global__ void k_stage2(const float* __restrict__ partial, int nparts,
                         unsigned short* __restrict__ centb)
{
    const int k = blockIdx.x;
    const int t = threadIdx.x;      // 512
    const int d = t & (DD - 1);
    const int slice = t >> 7;
    float a0 = 0.f, a1 = 0.f, a2 = 0.f, a3 = 0.f;
    int b = slice;
    for (; b + 12 < nparts; b += 16) {
        a0 += partial[((size_t)(b     ) * KK + k) * DD + d];
        a1 += partial[((size_t)(b +  4) * KK + k) * DD + d];
        a2 += partial[((size_t)(b +  8) * KK + k) * DD + d];
        a3 += partial[((size_t)(b + 12) * KK + k) * DD + d];
    }
    for (; b < nparts; b += 4)
        a0 += partial[((size_t)b * KK + k) * DD + d];
    const float s = (a0 + a1) + (a2 + a3);
    __shared__ float red[4][DD];
    red[slice][d] = s;
    __syncthreads();
    float v = 0.f;
    if (t < DD) v = red[0][d] + red[1][d] + red[2][d] + red[3][d];
    float sq = v * v;
#pragma unroll
    for (int m = 32; m > 0; m >>= 1) sq += __shfl_xor(sq, m);
    __shared__ float wsum[8];
    if ((t & 63) == 0) wsum[t >> 6] = sq;
    __syncthreads();
    if (t < DD) centb[k * DD + d] = f2bf(v * rsqrtf(wsum[0] + wsum[1]));
}

// ---------------- stage 3: R0-verbatim MFMA + loss; epilogue -> per-block slot (no atomic/memset) ----------------
__global__ __launch_bounds__(1024, 4) void k_stage3(
    const float* __restrict__ Xf, const int* __restrict__ labels,
    const unsigned short* __restrict__ centb,
    const float* __restrict__ hbias, float* __restrict__ lossb, int spb)
{
    __shared__ unsigned short Cl[KK * ROWB];
    __shared__ unsigned short Xl[TS * ROWB];
    __shared__ int   labs[TS];
    __shared__ float lred[32];

    const int tid = threadIdx.x;
    const float hb = *hbias;
    const float bias = (hb > 20.f) ? hb : log1pf(__expf(hb));
    const float pos_bias = bias;
    const float neg_bias = 9.f * bias + 0.05f;

    const uint4* csrc = (const uint4*)centb;
    for (int c = tid; c < KK * DD / 8; c += 1024) {
        const int row = c >> 4;
        const int col = (c & 15) << 3;
        *(uint4*)(&Cl[row * ROWB + col]) = csrc[c];
    }

    const int lane = tid & 63;
    const int wave = tid >> 6;       // 0..15
    const int m15  = lane & 15;
    const int q    = lane >> 4;
    const int kq   = q << 3;
    const int base = blockIdx.x * spb;
    float pos_acc = 0.f, neg_acc = 0.f;

    for (int t0 = 0; t0 < spb; t0 += TS) {
        __syncthreads();
        const float4* xsrc = (const float4*)(Xf + (size_t)(base + t0) * DD);
        for (int c = tid; c < TS * DD / 4; c += 1024) {
            const int row = c >> 5;
            const int col = (c & 31) << 2;
            const float4 v = xsrc[c];
            ushort4 pk = make_ushort4(f2bf(v.x), f2bf(v.y), f2bf(v.z), f2bf(v.w));
            *(ushort4*)(&Xl[row * ROWB + col]) = pk;
        }
        if (tid < TS) labs[tid] = labels[base + t0 + tid];
        __syncthreads();

        short8 afrag[4];
        const int arow = (wave << 4) + m15;
#pragma unroll
        for (int s = 0; s < 4; ++s)
            afrag[s] = *(const short8*)(&Xl[arow * ROWB + (s << 5) + kq]);

        float x2p = 0.f;
#pragma unroll
        for (int s = 0; s < 4; ++s)
#pragma unroll
            for (int j = 0; j < 8; ++j) {
                const float e = bf2f((unsigned short)afrag[s][j]);
                x2p = fmaf(e, e, x2p);
            }
        x2p += __shfl_xor(x2p, 16);
        x2p += __shfl_xor(x2p, 32);

        f32x4 acc[16];
#pragma unroll
        for (int t = 0; t < 16; ++t) acc[t] = (f32x4){0.f, 0.f, 0.f, 0.f};
#pragma unroll
        for (int t = 0; t < 16; ++t) {
            const int brow = (t << 4) + m15;
#pragma unroll
            for (int s = 0; s < 4; ++s) {
                const short8 bfrag = *(const short8*)(&Cl[brow * ROWB + (s << 5) + kq]);
                acc[t] = __builtin_amdgcn_mfma_f32_16x16x32_bf16(afrag[s], bfrag, acc[t], 0, 0, 0);
            }
        }

#pragma unroll
        for (int r = 0; r < 4; ++r) {
            const int ml = (wave << 4) + (q << 2) + r;
            const int l  = labs[ml];
            const float x2 = __shfl(x2p, (q << 2) + r, 16);
            float posd = -1e30f, negd = -1e30f;
#pragma unroll
            for (int t = 0; t < 16; ++t) {
                const int cl = (t << 4) + m15;
                const float v = acc[t][r];
                const bool isp = (cl == l);
                posd = isp ? v : posd;
                negd = isp ? negd : fmaxf(negd, v);
            }
#pragma unroll
            for (int m = 1; m < 16; m <<= 1) {
                posd = fmaxf(posd, __shfl_xor(posd, m));
                negd = fmaxf(negd, __shfl_xor(negd, m));
            }
            if (m15 == 0) {
                const float pd = x2 + 1.0f - 2.f * posd;
                const float nd = x2 + 1.0f - 2.f * negd;
                pos_acc += fmaxf(pd - pos_bias, 0.f);
                neg_acc += fmaxf(neg_bias - nd, 0.f);
            }
        }
    }

#pragma unroll
    for (int m = 32; m > 0; m >>= 1) {
        pos_acc += __shfl_xor(pos_acc, m);
        neg_acc += __shfl_xor(neg_acc, m);
    }
    if (lane == 0) { lred[wave] = pos_acc; lred[16 + wave] = neg_acc; }
    __syncthreads();
    if (tid == 0) {
        float p = 0.f, n = 0.f;
#pragma unroll
        for (int w = 0; w < 16; ++w) { p += lred[w]; n += lred[16 + w]; }
        lossb[2 * blockIdx.x]     = p;      // per-block slot: no atomics, no memset dispatch
        lossb[2 * blockIdx.x + 1] = n;
    }
}

// ---------------- final: deterministic sum of per-block loss slots ----------------
__global__ void k_final(const float* __restrict__ lb, float* __restrict__ out,
                        float invN, int G)
{
    const int t = threadIdx.x;   // 256
    float p = 0.f, n = 0.f;
    for (int i = t; i < G; i += 256) { p += lb[2 * i]; n += lb[2 * i + 1]; }
#pragma unroll
    for (int m = 32; m > 0; m >>= 1) { p += __shfl_xor(p, m); n += __shfl_xor(n, m); }
    __shared__ float sp[4], sn[4];
    const int w = t >> 6;
    if ((t & 63) == 0) { sp[w] = p; sn[w] = n; }
    __syncthreads();
    if (t == 0) {
        out[0] = 4.0f * (sp[0] + sp[1] + sp[2] + sp[3]) * invN;
        out[1] = (sn[0] + sn[1] + sn[2] + sn[3]) * invN;
    }
}

extern "C" void kernel_launch(void* const* d_in, const int* in_sizes, int n_in,
                              void* d_out, int out_size, void* d_ws, size_t ws_size,
                              hipStream_t stream)
{
    const float* X      = (const float*)d_in[0];
    // d_in[1] (scores) is dead in the reference forward — never read.
    const int*   labels = (const int*)d_in[2];
    const float* hbias  = (const float*)d_in[3];
    float* out = (float*)d_out;
    const int N = in_sizes[0] / DD;
    const int G = N / SPB1;                   // 256 blocks

    char* ws = (char*)d_ws;
    const size_t offC    = 4096;                        // lossb: [0, 2*G*4) = 2 KiB
    const size_t offPart = offC + (size_t)KK * DD * 2;  // centb: 64 KiB
    const size_t szPart  = (size_t)G * KK * DD * 4;     // 32 MiB

    float*          lossb   = (float*)ws;
    unsigned short* centb   = (unsigned short*)(ws + offC);
    float*          partial = (float*)(ws + offPart);

    const int mode   = (ws_size >= offPart + szPart) ? 0 : 2;
    const int nparts = (mode == 2) ? 1 : G;

    if (mode == 2) hipMemsetAsync(partial, 0, (size_t)KK * DD * 4, stream);

    if (mode == 0) k_stage1_gather<0><<<G, 1024, 0, stream>>>(X, labels, partial);
    else           k_stage1_gather<2><<<G, 1024, 0, stream>>>(X, labels, partial);

    k_stage2<<<KK, 512, 0, stream>>>(partial, nparts, centb);

    k_stage3<<<G, 1024, 0, stream>>>(X, labels, centb, hbias, lossb, N / G);

    k_final<<<1, 256, 0, stream>>>(lossb, out, 1.0f / (float)N, G);
}